// Round 3
// baseline (36.679 us; speedup 1.0000x reference)
//
#include <hip/hip_runtime.h>

// Problem constants (from reference)
constexpr int NC = 2;   // N_CLASSES
constexpr int NF = 10;  // N_FEATURES
constexpr int PD = 10;  // PSI_DIM

constexpr int THREADS = 64;                        // ONE wave per block -> no s_barrier
constexpr int F4_PER_THREAD = 5;                   // 1 row-pair = 20 floats = 5 float4
constexpr int TILE_F4 = THREADS * F4_PER_THREAD;   // 320 float4
constexpr int TILE_FLOATS = TILE_F4 * 4;           // 1280 floats = 5120 B per buffer

// Single-wave, double-buffered, barrier-free streaming kernel.
//   Phase 0: lanes 0..19 compute M_r[k][a]; broadcast via LDS.
//   Loop (T3/T4-lite): issue 5 global_load_lds for tile k+1 into buf^1, then
//   s_waitcnt vmcnt(counted) so tile k's 5 loads are retired while the 5 new
//   ones (and the previous out-store) STAY IN FLIGHT. No vmcnt(0) in the loop,
//   no barriers (the wave consumes exactly the LDS region it staged itself).
__global__ __launch_bounds__(THREADS) void fused_dbuf_kernel(
        const float* __restrict__ x,
        const float* __restrict__ psi_r,
        const float* __restrict__ psi_i,
        const float* __restrict__ A_r,
        const float* __restrict__ A_i,
        float* __restrict__ out,
        int T2, long totalF4, int nTiles) {
    __shared__ float Msh[NC * NF];
    __shared__ float tile[2][TILE_FLOATS];   // 2 x 5 KB

    const int t = threadIdx.x;

    // ---- Phase 0: M_r[k,a] = sum_{i,j} (pr_i*Ar[k,i,j,a] - pi_i*Ai[k,i,j,a]) * (pr_j - pi_j)
    if (t < NC * NF) {
        int k = t / NF, a = t - k * NF;
        float acc = 0.f;
#pragma unroll
        for (int i = 0; i < PD; ++i) {
            float pri = psi_r[i], pii = psi_i[i];
#pragma unroll
            for (int j = 0; j < PD; ++j) {
                float dj = psi_r[j] - psi_i[j];
                int idx = ((k * PD + i) * PD + j) * NF + a;
                acc = fmaf(pri * A_r[idx] - pii * A_i[idx], dj, acc);
            }
        }
        Msh[t] = acc;
    }
    __syncthreads();   // once, before the loop (single wave: just a waitcnt)

    float m0[NF], m1[NF];
#pragma unroll
    for (int a = 0; a < NF; ++a) {
        m0[a] = Msh[a];
        m1[a] = Msh[NF + a];
    }

    const float4* x4 = reinterpret_cast<const float4*>(x);
    float4* out4 = reinterpret_cast<float4*>(out);
    const int G = (int)gridDim.x;

    // Stage tile `tileIdx` into tile[buf]: 5 chunks of 64 float4, coalesced,
    // wave-uniform LDS base (HW adds lane*16B). Buffer ends up in exact linear
    // row order: global float4 g -> buf floats [4*(g-base4), +4).
    auto STAGE = [&](int buf, int tileIdx) {
        const long base4 = (long)tileIdx * TILE_F4;
#pragma unroll
        for (int q = 0; q < F4_PER_THREAD; ++q) {
            long g4 = base4 + (long)q * THREADS + t;
            if (g4 >= totalF4) g4 = totalF4 - 1;  // duplicate read, never stored
            const float* ldsdst = &tile[buf][q * (THREADS * 4)];
            __builtin_amdgcn_global_load_lds(
                (const __attribute__((address_space(1))) void*)(x4 + g4),
                (__attribute__((address_space(3))) void*)ldsdst,
                16, 0, 0);
        }
    };

    int cur = 0;
    const int firstTile = (int)blockIdx.x;
    if (firstTile < nTiles) STAGE(0, firstTile);

    int iter = 0;
    for (int k = firstTile; k < nTiles; k += G, ++iter) {
        const int next = k + G;
        const bool hasNext = next < nTiles;
        if (hasNext) STAGE(cur ^ 1, next);

        // Counted wait: FIFO = [5 loads(tile k), (store k-1), 5 loads(tile k+1)].
        // Allow the newest (hasNext?5:0) loads + (iter?1:0) store to remain
        // outstanding => tile k's loads are retired. Never vmcnt(0) mid-loop.
        const int n = (hasNext ? 5 : 0) + (iter ? 1 : 0);
        if (n == 6)      asm volatile("s_waitcnt vmcnt(6)" ::: "memory");
        else if (n == 5) asm volatile("s_waitcnt vmcnt(5)" ::: "memory");
        else if (n == 1) asm volatile("s_waitcnt vmcnt(1)" ::: "memory");
        else             asm volatile("s_waitcnt vmcnt(0)" ::: "memory");

        // ---- compute: one row-pair per lane (80 B contiguous in LDS) ----
        const int rp = k * THREADS + t;
        const float4* lp = reinterpret_cast<const float4*>(&tile[cur][t * 20]);
        float4 v0 = lp[0], v1 = lp[1], v2 = lp[2], v3 = lp[3], v4 = lp[4];
        float r0[NF] = {v0.x, v0.y, v0.z, v0.w, v1.x, v1.y, v1.z, v1.w, v2.x, v2.y};
        float r1[NF] = {v2.z, v2.w, v3.x, v3.y, v3.z, v3.w, v4.x, v4.y, v4.z, v4.w};
        float4 o = {0.f, 0.f, 0.f, 0.f};
#pragma unroll
        for (int a = 0; a < NF; ++a) {
            o.x = fmaf(r0[a], m0[a], o.x);
            o.y = fmaf(r0[a], m1[a], o.y);
            o.z = fmaf(r1[a], m0[a], o.z);
            o.w = fmaf(r1[a], m1[a], o.w);
        }
        if (rp < T2) out4[rp] = o;

        asm volatile("" ::: "memory");  // pin issue order at iteration boundary
        cur ^= 1;
    }
}

extern "C" void kernel_launch(void* const* d_in, const int* in_sizes, int n_in,
                              void* d_out, int out_size, void* d_ws, size_t ws_size,
                              hipStream_t stream) {
    const float* x     = (const float*)d_in[0];
    const float* psi_r = (const float*)d_in[1];
    const float* psi_i = (const float*)d_in[2];
    const float* A_r   = (const float*)d_in[3];
    const float* A_i   = (const float*)d_in[4];
    float* out = (float*)d_out;

    const int T = in_sizes[0] / NF;        // 4,000,000 rows
    const int T2 = T / 2;                  // 2,000,000 row-pairs
    const long totalF4 = (long)in_sizes[0] / 4;
    const int nTiles = (T2 + THREADS - 1) / THREADS;   // 31250

    // ~15 blocks/CU resident (10.3 KB LDS each); persistent grid-stride.
    int blocks = 14 * 256;
    if (blocks > nTiles) blocks = nTiles;

    fused_dbuf_kernel<<<blocks, THREADS, 0, stream>>>(
        x, psi_r, psi_i, A_r, A_i, out, T2, totalF4, nTiles);
}